// Round 1
// baseline (49.150 us; speedup 1.0000x reference)
//
#include <hip/hip_runtime.h>

#define BB 64
#define NN 3000
#define MM 128
#define NBINS 1280
#define NSEL 128

// ---------------- Kernel 1: IoU + argmax + candidate deltas + packed masks ----
// packed[n] = posmult(11b) | negmult(11b)<<11 | gtlabel(5b)<<22
__global__ __launch_bounds__(256) void k1_iou(
    const float4* __restrict__ roi, const float4* __restrict__ gt,
    const int* __restrict__ gtl, const int* __restrict__ rpos,
    const int* __restrict__ rneg, int* __restrict__ packed,
    float4* __restrict__ deltas)
{
  #pragma clang fp contract(off)
  const int b = blockIdx.y;
  const int n = blockIdx.x * 256 + threadIdx.x;
  __shared__ float4 g[MM];
  __shared__ float  ga[MM];
  __shared__ int    gl[MM];
  if (threadIdx.x < MM) {
    float4 v = gt[b * MM + threadIdx.x];
    g[threadIdx.x]  = v;
    ga[threadIdx.x] = (v.z - v.x) * (v.w - v.y);
    gl[threadIdx.x] = gtl[b * MM + threadIdx.x];
  }
  __syncthreads();
  if (n >= NN) return;
  float4 r = roi[b * NN + n];
  float ar = (r.z - r.x) * (r.w - r.y);
  float best = -1.0f; int bi = 0;
  for (int m = 0; m < MM; ++m) {
    float4 gm = g[m];
    float iy1 = fmaxf(r.x, gm.x);
    float ix1 = fmaxf(r.y, gm.y);
    float iy2 = fminf(r.z, gm.z);
    float ix2 = fminf(r.w, gm.w);
    float inter = fmaxf(iy2 - iy1, 0.0f) * fmaxf(ix2 - ix1, 0.0f);
    float iou = inter / (ar + ga[m] - inter + 1e-7f);  // IEEE div, matches np
    if (iou > best) { best = iou; bi = m; }            // strict > keeps first (argmax)
  }
  int pm = (best > 0.5f) ? rpos[b * NN + n] : 0;
  int nm = (best < 0.5f && best > 0.1f) ? rneg[b * NN + n] : 0;
  packed[b * NN + n] = pm | (nm << 11) | (gl[bi] << 22);

  // candidate deltas vs gt_boxes[best_gt] (only consumed when pos-selected)
  float4 gg = g[bi];
  float bw = r.w - r.y, bh = r.z - r.x;
  float bcx = r.y + 0.5f * bw, bcy = r.x + 0.5f * bh;
  float gw = gg.w - gg.y, gh = gg.z - gg.x;
  float gcx = gg.y + 0.5f * gw, gcy = gg.x + 0.5f * gh;
  bw = (bw == 0.0f) ? 0.001f : bw;
  bh = (bh == 0.0f) ? 0.001f : bh;
  float dx = (gw == 0.0f) ? 0.0f : (gcx - bcx) / bw;
  float dy = (gh == 0.0f) ? 0.0f : (gcy - bcy) / bh;
  float dw = (gw == 0.0f) ? 0.0f : logf(gw / bw);
  float dh = (gh == 0.0f) ? 0.0f : logf(gh / bh);
  // divide by VARIANCES with real IEEE division by 0.1f/0.2f (NOT *10/*5)
  deltas[b * NN + n] = make_float4(dy / 0.1f, dx / 0.1f, dh / 0.2f, dw / 0.2f);
}

// ---------------- Kernel 2: stable top-128 selection per batch ---------------
// Exactly reproduces: rank = position in stable descending sort of mask*rand;
// selected iff masked && rank < 128.  (Ties broken by lowest index.)
__global__ __launch_bounds__(1024) void k2_select(const int* __restrict__ packed,
                                                  int* __restrict__ labels)
{
  const int b = blockIdx.x;
  const int tid = threadIdx.x;
  __shared__ int sp[NN];
  __shared__ unsigned hist[2048];   // pos count (low16) | neg count (high16)
  __shared__ unsigned csum[1024];
  __shared__ int sTvP, sQp, sTvN, sQn;

  for (int i = tid; i < NN; i += 1024) sp[i] = packed[b * NN + i];
  hist[tid] = 0; hist[tid + 1024] = 0;
  if (tid == 0) { sTvP = 0; sQp = 0; sTvN = 0; sQn = 0; }
  __syncthreads();
  for (int i = tid; i < NN; i += 1024) {
    int p = sp[i];
    int pm = p & 0x7FF, nm = (p >> 11) & 0x7FF;
    if (pm) atomicAdd(&hist[pm], 1u);
    if (nm) atomicAdd(&hist[nm], 0x10000u);
  }
  __syncthreads();
  // inclusive suffix scan over 2048 bins (Hillis-Steele, both fields packed)
  for (int off = 1; off < 2048; off <<= 1) {
    unsigned a0 = hist[tid];
    unsigned a1 = hist[tid + 1024];
    if (tid + off < 2048)        a0 += hist[tid + off];
    if (tid + 1024 + off < 2048) a1 += hist[tid + 1024 + off];
    __syncthreads();
    hist[tid] = a0; hist[tid + 1024] = a1;
    __syncthreads();
  }
  // Tv = largest v with suffix(v) >= 128 ; quota = 128 - suffix(v+1)
  for (int k = 0; k < 2; ++k) {
    int v = tid + k * 1024;
    if (v >= 1 && v < NBINS) {
      unsigned s0 = hist[v] & 0xFFFFu;
      unsigned s1 = hist[v + 1] & 0xFFFFu;
      if (s0 >= NSEL && s1 < NSEL) { sTvP = v; sQp = NSEL - (int)s1; }
      unsigned t0 = hist[v] >> 16;
      unsigned t1 = hist[v + 1] >> 16;
      if (t0 >= NSEL && t1 < NSEL) { sTvN = v; sQn = NSEL - (int)t1; }
    }
  }
  __syncthreads();
  const int Tp = sTvP, Tn = sTvN, Qp = sQp, Qn = sQn;
  // tie-rank: thread t owns contiguous chunk [3t, 3t+3)
  const int n0 = tid * 3;
  unsigned cc = 0;
  for (int j = 0; j < 3; ++j) {
    int n = n0 + j;
    if (n < NN) {
      int p = sp[n];
      if (Tp && (p & 0x7FF) == Tp) cc += 1u;
      if (Tn && ((p >> 11) & 0x7FF) == Tn) cc += 0x10000u;
    }
  }
  csum[tid] = cc;
  __syncthreads();
  for (int off = 1; off < 1024; off <<= 1) {
    unsigned v = csum[tid];
    if (tid >= off) v += csum[tid - off];
    __syncthreads();
    csum[tid] = v;
    __syncthreads();
  }
  unsigned excl = csum[tid] - cc;
  int ep = (int)(excl & 0xFFFFu), en = (int)(excl >> 16);
  for (int j = 0; j < 3; ++j) {
    int n = n0 + j;
    if (n >= NN) break;
    int p = sp[n];
    int pm = p & 0x7FF, nm = (p >> 11) & 0x7FF;
    bool selp, seln;
    if (pm > Tp) selp = true;
    else if (pm == Tp && pm > 0) { selp = (ep < Qp); ep++; }
    else selp = false;
    if (nm > Tn) seln = true;
    else if (nm == Tn && nm > 0) { seln = (en < Qn); en++; }
    else seln = false;
    int lab = selp ? ((p >> 22) & 0x1F) : (seln ? 0 : -1);
    labels[b * NN + n] = lab;
  }
}

// ---------------- Kernel 3: expansion to one-hot outputs ---------------------
__global__ __launch_bounds__(256) void k3_expand(
    const int* __restrict__ labels, const float4* __restrict__ deltas,
    float4* __restrict__ out1, float* __restrict__ out2)
{
  const int total = BB * NN * 21;
  for (int u = blockIdx.x * blockDim.x + threadIdx.x; u < total;
       u += gridDim.x * blockDim.x) {
    int nl = u / 21;
    int c = u - nl * 21;
    int lab = labels[nl];
    float4 v = make_float4(0.f, 0.f, 0.f, 0.f);
    if (c == lab && lab > 0) v = deltas[nl];
    out1[u] = v;
    out2[u] = (c == lab) ? 1.0f : 0.0f;
  }
}

extern "C" void kernel_launch(void* const* d_in, const int* in_sizes, int n_in,
                              void* d_out, int out_size, void* d_ws, size_t ws_size,
                              hipStream_t stream) {
  const float4* roi = (const float4*)d_in[0];
  const float4* gt  = (const float4*)d_in[1];
  const int* gtl  = (const int*)d_in[2];
  const int* rpos = (const int*)d_in[3];
  const int* rneg = (const int*)d_in[4];

  char* ws = (char*)d_ws;
  int*    packed = (int*)ws;                         // B*N ints   (768 KB)
  int*    labels = (int*)(ws + 768000);              // B*N ints   (768 KB)
  float4* deltas = (float4*)(ws + 1536000);          // B*N float4 (3 MB)

  float4* out1 = (float4*)d_out;                            // B*N*21 float4
  float*  out2 = (float*)d_out + (size_t)BB * NN * 21 * 4;  // B*N*21 floats

  dim3 g1((NN + 255) / 256, BB);
  k1_iou<<<g1, 256, 0, stream>>>(roi, gt, gtl, rpos, rneg, packed, deltas);
  k2_select<<<BB, 1024, 0, stream>>>(packed, labels);
  k3_expand<<<4096, 256, 0, stream>>>(labels, deltas, out1, out2);
}

// Round 2
// 48.080 us; speedup vs baseline: 1.0223x; 1.0223x over previous
//
#include <hip/hip_runtime.h>

#define BB 64
#define NN 3000
#define MM 128
#define NBINS 1280
#define NSEL 128

// ---------------- Kernel 1: zero out1 + IoU + argmax + deltas + packed masks --
// packed[n] = posmult(11b) | negmult(11b)<<11 | gtlabel(5b)<<22
__global__ __launch_bounds__(256) void k1_iou(
    const float4* __restrict__ roi, const float4* __restrict__ gt,
    const int* __restrict__ gtl, const int* __restrict__ rpos,
    const int* __restrict__ rneg, int* __restrict__ packed,
    float4* __restrict__ deltas, float4* __restrict__ out1z)
{
  #pragma clang fp contract(off)
  const int b = blockIdx.y;
  const int n = blockIdx.x * 256 + threadIdx.x;
  const bool valid = (n < NN);
  __shared__ float4 g[MM];
  __shared__ float  ga[MM];
  __shared__ int    gl[MM];

  // issue roi load BEFORE the barrier so the barrier's vmcnt(0) covers it
  float4 r = roi[b * NN + (valid ? n : 0)];
  if (threadIdx.x < MM) {
    float4 v = gt[b * MM + threadIdx.x];
    g[threadIdx.x]  = v;
    ga[threadIdx.x] = (v.z - v.x) * (v.w - v.y);
    gl[threadIdx.x] = gtl[b * MM + threadIdx.x];
  }
  __syncthreads();

  // fire-and-forget zeroing of out1 (4,032,000 float4 = 64.5 MB); drains
  // under the VALU loop below (no further barriers / global loads in kernel)
  {
    const float4 z = make_float4(0.f, 0.f, 0.f, 0.f);
    const int gid = (blockIdx.y * gridDim.x + blockIdx.x) * 256 + threadIdx.x;
    for (int i = gid; i < BB * NN * 21; i += 768 * 256) out1z[i] = z;
  }

  if (!valid) return;
  float ar = (r.z - r.x) * (r.w - r.y);
  float best = -1.0f; int bi = 0;
  #pragma unroll 4
  for (int m = 0; m < MM; ++m) {
    float4 gm = g[m];
    float iy1 = fmaxf(r.x, gm.x);
    float ix1 = fmaxf(r.y, gm.y);
    float iy2 = fminf(r.z, gm.z);
    float ix2 = fminf(r.w, gm.w);
    float inter = fmaxf(iy2 - iy1, 0.0f) * fmaxf(ix2 - ix1, 0.0f);
    float iou = inter / (ar + ga[m] - inter + 1e-7f);  // IEEE div, matches np
    if (iou > best) { best = iou; bi = m; }            // strict > = first argmax
  }
  int pm = (best > 0.5f) ? rpos[b * NN + n] : 0;
  int nm = (best < 0.5f && best > 0.1f) ? rneg[b * NN + n] : 0;
  packed[b * NN + n] = pm | (nm << 11) | (gl[bi] << 22);

  float4 gg = g[bi];
  float bw = r.w - r.y, bh = r.z - r.x;
  float bcx = r.y + 0.5f * bw, bcy = r.x + 0.5f * bh;
  float gw = gg.w - gg.y, gh = gg.z - gg.x;
  float gcx = gg.y + 0.5f * gw, gcy = gg.x + 0.5f * gh;
  bw = (bw == 0.0f) ? 0.001f : bw;
  bh = (bh == 0.0f) ? 0.001f : bh;
  float dx = (gw == 0.0f) ? 0.0f : (gcx - bcx) / bw;
  float dy = (gh == 0.0f) ? 0.0f : (gcy - bcy) / bh;
  float dw = (gw == 0.0f) ? 0.0f : logf(gw / bw);
  float dh = (gh == 0.0f) ? 0.0f : logf(gh / bh);
  deltas[b * NN + n] = make_float4(dy / 0.1f, dx / 0.1f, dh / 0.2f, dw / 0.2f);
}

// ---------------- Kernel 2: top-128 selection + output writes ----------------
// Reproduces exactly: rank = position in stable descending sort of mask*rand;
// selected iff masked && rank < 128 (ties broken by lowest index).
__global__ __launch_bounds__(1024) void k2_select(
    const int* __restrict__ packed, const float4* __restrict__ deltas,
    float4* __restrict__ out1, float* __restrict__ out2)
{
  const int b = blockIdx.x;
  const int tid = threadIdx.x;
  const int lane = tid & 63;
  const int wave = tid >> 6;
  __shared__ int sp[NN];              // packed, later reused for labels
  __shared__ unsigned hist[NBINS + 1]; // pos count low16 | neg count high16
  __shared__ unsigned wsum[16];
  __shared__ int sT[4];               // Tp, Qp, Tn, Qn

  for (int i = tid; i < NBINS + 1; i += 1024) hist[i] = 0;
  if (tid == 0) { sT[0] = 0; sT[1] = 0; sT[2] = 0; sT[3] = 0; }
  __syncthreads();                                        // B1

  for (int i = tid; i < NN; i += 1024) {
    int p = packed[b * NN + i];
    sp[i] = p;
    int pm = p & 0x7FF, nm = (p >> 11) & 0x7FF;
    if (pm) atomicAdd(&hist[pm], 1u);
    if (nm) atomicAdd(&hist[nm], 0x10000u);
  }
  __syncthreads();                                        // B2

  // single-wave register suffix scan over 1280 bins (20 bins/lane, packed)
  if (wave == 0) {
    unsigned cs[21];
    const int base = 1 + lane * 20;
    cs[20] = 0;
    #pragma unroll
    for (int j = 19; j >= 0; --j) cs[j] = cs[j + 1] + hist[base + j];
    unsigned tot = cs[0];
    unsigned run = tot;
    #pragma unroll
    for (int off = 1; off < 64; off <<= 1) {
      unsigned u = __shfl_down(run, off);
      if (lane + off < 64) run += u;
    }
    unsigned above = run - tot;  // suffix over lanes > lane
    #pragma unroll
    for (int j = 0; j < 20; ++j) {
      int bin = base + j;
      unsigned s  = cs[j] + above;
      unsigned sn = cs[j + 1] + above;
      unsigned ps = s & 0xFFFFu, psn = sn & 0xFFFFu;
      if (ps >= NSEL && psn < NSEL) { sT[0] = bin; sT[1] = NSEL - (int)psn; }
      unsigned ns = s >> 16, nsn = sn >> 16;
      if (ns >= NSEL && nsn < NSEL) { sT[2] = bin; sT[3] = NSEL - (int)nsn; }
    }
  }
  __syncthreads();                                        // B3
  const int Tp = sT[0], Qp = sT[1], Tn = sT[2], Qn = sT[3];

  // tie-rank: thread t owns contiguous chunk [3t, 3t+3)
  const int n0 = tid * 3;
  int p0 = 0, p1 = 0, p2 = 0;
  if (n0     < NN) p0 = sp[n0];
  if (n0 + 1 < NN) p1 = sp[n0 + 1];
  if (n0 + 2 < NN) p2 = sp[n0 + 2];
  unsigned cc = 0;
  {
    int q[3] = {p0, p1, p2};
    #pragma unroll
    for (int j = 0; j < 3; ++j) {
      int pm = q[j] & 0x7FF, nm = (q[j] >> 11) & 0x7FF;
      if (Tp && pm == Tp) cc += 1u;
      if (Tn && nm == Tn) cc += 0x10000u;
    }
  }
  unsigned inc = cc;
  #pragma unroll
  for (int off = 1; off < 64; off <<= 1) {
    unsigned u = __shfl_up(inc, off);
    if (lane >= off) inc += u;
  }
  if (lane == 63) wsum[wave] = inc;
  __syncthreads();                                        // B4
  unsigned woff = 0;
  for (int w = 0; w < wave; ++w) woff += wsum[w];
  unsigned excl = woff + (inc - cc);
  int ep = (int)(excl & 0xFFFFu), en = (int)(excl >> 16);

  // selection + sparse out1 writes + labels back into sp
  int q[3] = {p0, p1, p2};
  #pragma unroll
  for (int j = 0; j < 3; ++j) {
    int n = n0 + j;
    if (n >= NN) break;
    int p = q[j];
    int pm = p & 0x7FF, nm = (p >> 11) & 0x7FF;
    bool selp;
    if (pm > Tp) selp = true;
    else if (pm && pm == Tp) { selp = (ep < Qp); ep++; }
    else selp = false;
    bool seln;
    if (nm > Tn) seln = true;
    else if (nm && nm == Tn) { seln = (en < Qn); en++; }
    else seln = false;
    int lab = selp ? ((p >> 22) & 0x1F) : (seln ? 0 : -1);
    sp[n] = lab;
    if (lab > 0) {
      size_t nl = (size_t)b * NN + n;
      out1[nl * 21 + lab] = deltas[nl];   // out1 row pre-zeroed by k1
    }
  }
  __syncthreads();                                        // B5

  // dense, coalesced out2 for this batch (no pre-zero needed)
  float* o2 = out2 + (size_t)b * NN * 21;
  for (int u = tid; u < NN * 21; u += 1024) {
    int n = u / 21;
    int c = u - n * 21;
    o2[u] = (c == sp[n]) ? 1.0f : 0.0f;
  }
}

extern "C" void kernel_launch(void* const* d_in, const int* in_sizes, int n_in,
                              void* d_out, int out_size, void* d_ws, size_t ws_size,
                              hipStream_t stream) {
  const float4* roi = (const float4*)d_in[0];
  const float4* gt  = (const float4*)d_in[1];
  const int* gtl  = (const int*)d_in[2];
  const int* rpos = (const int*)d_in[3];
  const int* rneg = (const int*)d_in[4];

  char* ws = (char*)d_ws;
  int*    packed = (int*)ws;                    // B*N ints (768 KB)
  float4* deltas = (float4*)(ws + (1 << 20));   // B*N float4 (3 MB)

  float4* out1 = (float4*)d_out;                            // B*N*21 float4
  float*  out2 = (float*)d_out + (size_t)BB * NN * 21 * 4;  // B*N*21 floats

  dim3 g1((NN + 255) / 256, BB);
  k1_iou<<<g1, 256, 0, stream>>>(roi, gt, gtl, rpos, rneg, packed, deltas, out1);
  k2_select<<<BB, 1024, 0, stream>>>(packed, deltas, out1, out2);
}

// Round 3
// 47.455 us; speedup vs baseline: 1.0357x; 1.0132x over previous
//
#include <hip/hip_runtime.h>

#define BB 64
#define NN 3000
#define MM 128
#define NBINS 1280
#define NSEL 128

// ---------------- Kernel 0: zero-fill ALL of d_out (fill-clone pattern) ------
// out_size = 20,160,000 floats = 5,040,000 float4. One float4 per thread,
// exactly like __amd_rocclr_fillBufferAligned (measured 6.6-6.8 TB/s here).
__global__ __launch_bounds__(256) void k0_zero(float4* __restrict__ o, int n4)
{
  int i = blockIdx.x * 256 + threadIdx.x;
  if (i < n4) o[i] = make_float4(0.f, 0.f, 0.f, 0.f);
}

// ---------------- Kernel 1: IoU + argmax + deltas + packed masks -------------
// packed[n] = posmult(11b) | negmult(11b)<<11 | gtlabel(5b)<<22
__global__ __launch_bounds__(256) void k1_iou(
    const float4* __restrict__ roi, const float4* __restrict__ gt,
    const int* __restrict__ gtl, const int* __restrict__ rpos,
    const int* __restrict__ rneg, int* __restrict__ packed,
    float4* __restrict__ deltas)
{
  #pragma clang fp contract(off)
  const int b = blockIdx.y;
  const int n = blockIdx.x * 256 + threadIdx.x;
  const bool valid = (n < NN);
  __shared__ float4 g[MM];
  __shared__ float  ga[MM];
  __shared__ int    gl[MM];

  float4 r = roi[b * NN + (valid ? n : 0)];
  if (threadIdx.x < MM) {
    float4 v = gt[b * MM + threadIdx.x];
    g[threadIdx.x]  = v;
    ga[threadIdx.x] = (v.z - v.x) * (v.w - v.y);
    gl[threadIdx.x] = gtl[b * MM + threadIdx.x];
  }
  __syncthreads();
  if (!valid) return;

  float ar = (r.z - r.x) * (r.w - r.y);
  float best = -1.0f; int bi = 0;
  #pragma unroll 4
  for (int m = 0; m < MM; ++m) {
    float4 gm = g[m];
    float iy1 = fmaxf(r.x, gm.x);
    float ix1 = fmaxf(r.y, gm.y);
    float iy2 = fminf(r.z, gm.z);
    float ix2 = fminf(r.w, gm.w);
    float inter = fmaxf(iy2 - iy1, 0.0f) * fmaxf(ix2 - ix1, 0.0f);
    float iou = inter / (ar + ga[m] - inter + 1e-7f);  // IEEE div = np bitwise
    if (iou > best) { best = iou; bi = m; }            // strict > = first argmax
  }
  int pm = (best > 0.5f) ? rpos[b * NN + n] : 0;
  int nm = (best < 0.5f && best > 0.1f) ? rneg[b * NN + n] : 0;
  packed[b * NN + n] = pm | (nm << 11) | (gl[bi] << 22);

  float4 gg = g[bi];
  float bw = r.w - r.y, bh = r.z - r.x;
  float bcx = r.y + 0.5f * bw, bcy = r.x + 0.5f * bh;
  float gw = gg.w - gg.y, gh = gg.z - gg.x;
  float gcx = gg.y + 0.5f * gw, gcy = gg.x + 0.5f * gh;
  bw = (bw == 0.0f) ? 0.001f : bw;
  bh = (bh == 0.0f) ? 0.001f : bh;
  float dx = (gw == 0.0f) ? 0.0f : (gcx - bcx) / bw;
  float dy = (gh == 0.0f) ? 0.0f : (gcy - bcy) / bh;
  float dw = (gw == 0.0f) ? 0.0f : logf(gw / bw);
  float dh = (gh == 0.0f) ? 0.0f : logf(gh / bh);
  deltas[b * NN + n] = make_float4(dy / 0.1f, dx / 0.1f, dh / 0.2f, dw / 0.2f);
}

// ---------------- Kernel 2: top-128 selection + SPARSE scatter ---------------
// rank = position in stable descending sort of mask*rand; selected iff
// masked && rank < 128 (ties by lowest index). Writes only nonzero outputs
// (out buffers pre-zeroed by k0): <=128 pos float4+1.0 and <=128 neg 1.0
// per batch.
__global__ __launch_bounds__(1024) void k2_select(
    const int* __restrict__ packed, const float4* __restrict__ deltas,
    float4* __restrict__ out1, float* __restrict__ out2)
{
  const int b = blockIdx.x;
  const int tid = threadIdx.x;
  const int lane = tid & 63;
  const int wave = tid >> 6;
  __shared__ int sp[NN];
  __shared__ unsigned hist[NBINS + 1];  // pos count low16 | neg count high16
  __shared__ unsigned wsum[16];
  __shared__ int sT[4];                 // Tp, Qp, Tn, Qn

  for (int i = tid; i < NBINS + 1; i += 1024) hist[i] = 0;
  if (tid == 0) { sT[0] = 0; sT[1] = 0; sT[2] = 0; sT[3] = 0; }
  __syncthreads();

  for (int i = tid; i < NN; i += 1024) {
    int p = packed[b * NN + i];
    sp[i] = p;
    int pm = p & 0x7FF, nm = (p >> 11) & 0x7FF;
    if (pm) atomicAdd(&hist[pm], 1u);
    if (nm) atomicAdd(&hist[nm], 0x10000u);
  }
  __syncthreads();

  // single-wave register suffix scan over 1280 bins (20 bins/lane, packed)
  if (wave == 0) {
    unsigned cs[21];
    const int base = 1 + lane * 20;
    cs[20] = 0;
    #pragma unroll
    for (int j = 19; j >= 0; --j) cs[j] = cs[j + 1] + hist[base + j];
    unsigned tot = cs[0];
    unsigned run = tot;
    #pragma unroll
    for (int off = 1; off < 64; off <<= 1) {
      unsigned u = __shfl_down(run, off);
      if (lane + off < 64) run += u;
    }
    unsigned above = run - tot;  // suffix over lanes > lane
    #pragma unroll
    for (int j = 0; j < 20; ++j) {
      int bin = base + j;
      unsigned s  = cs[j] + above;
      unsigned sn = cs[j + 1] + above;
      unsigned ps = s & 0xFFFFu, psn = sn & 0xFFFFu;
      if (ps >= NSEL && psn < NSEL) { sT[0] = bin; sT[1] = NSEL - (int)psn; }
      unsigned ns = s >> 16, nsn = sn >> 16;
      if (ns >= NSEL && nsn < NSEL) { sT[2] = bin; sT[3] = NSEL - (int)nsn; }
    }
  }
  __syncthreads();
  const int Tp = sT[0], Qp = sT[1], Tn = sT[2], Qn = sT[3];

  // tie-rank: thread t owns contiguous chunk [3t, 3t+3)
  const int n0 = tid * 3;
  int q[3] = {0, 0, 0};
  if (n0     < NN) q[0] = sp[n0];
  if (n0 + 1 < NN) q[1] = sp[n0 + 1];
  if (n0 + 2 < NN) q[2] = sp[n0 + 2];
  unsigned cc = 0;
  #pragma unroll
  for (int j = 0; j < 3; ++j) {
    int pm = q[j] & 0x7FF, nm = (q[j] >> 11) & 0x7FF;
    if (Tp && pm == Tp) cc += 1u;
    if (Tn && nm == Tn) cc += 0x10000u;
  }
  unsigned inc = cc;
  #pragma unroll
  for (int off = 1; off < 64; off <<= 1) {
    unsigned u = __shfl_up(inc, off);
    if (lane >= off) inc += u;
  }
  if (lane == 63) wsum[wave] = inc;
  __syncthreads();
  unsigned woff = 0;
  for (int w = 0; w < wave; ++w) woff += wsum[w];
  unsigned excl = woff + (inc - cc);
  int ep = (int)(excl & 0xFFFFu), en = (int)(excl >> 16);

  // selection + sparse scatter into pre-zeroed outputs
  #pragma unroll
  for (int j = 0; j < 3; ++j) {
    int n = n0 + j;
    if (n >= NN) break;
    int p = q[j];
    int pm = p & 0x7FF, nm = (p >> 11) & 0x7FF;
    bool selp;
    if (pm > Tp) selp = true;
    else if (pm && pm == Tp) { selp = (ep < Qp); ep++; }
    else selp = false;
    bool seln;
    if (nm > Tn) seln = true;
    else if (nm && nm == Tn) { seln = (en < Qn); en++; }
    else seln = false;
    if (selp | seln) {
      size_t nl = (size_t)b * NN + n;
      int lab = selp ? ((p >> 22) & 0x1F) : 0;
      out2[nl * 21 + lab] = 1.0f;
      if (lab > 0) out1[nl * 21 + lab] = deltas[nl];
    }
  }
}

extern "C" void kernel_launch(void* const* d_in, const int* in_sizes, int n_in,
                              void* d_out, int out_size, void* d_ws, size_t ws_size,
                              hipStream_t stream) {
  const float4* roi = (const float4*)d_in[0];
  const float4* gt  = (const float4*)d_in[1];
  const int* gtl  = (const int*)d_in[2];
  const int* rpos = (const int*)d_in[3];
  const int* rneg = (const int*)d_in[4];

  char* ws = (char*)d_ws;
  int*    packed = (int*)ws;                    // B*N ints (768 KB)
  float4* deltas = (float4*)(ws + (1 << 20));   // B*N float4 (3 MB)

  float4* out1 = (float4*)d_out;                            // B*N*21 float4
  float*  out2 = (float*)d_out + (size_t)BB * NN * 21 * 4;  // B*N*21 floats

  const int n4 = (BB * NN * 21 * 5) / 4;   // 5,040,000 float4 = whole d_out
  k0_zero<<<(n4 + 255) / 256, 256, 0, stream>>>((float4*)d_out, n4);
  dim3 g1((NN + 255) / 256, BB);
  k1_iou<<<g1, 256, 0, stream>>>(roi, gt, gtl, rpos, rneg, packed, deltas);
  k2_select<<<BB, 1024, 0, stream>>>(packed, deltas, out1, out2);
}

// Round 4
// 47.043 us; speedup vs baseline: 1.0448x; 1.0088x over previous
//
#include <hip/hip_runtime.h>

#define BB 64
#define NN 3000
#define MM 128
#define NBINS 1280
#define NSEL 128
#define ZB 1024          // zero-fill blocks (blocks [0, ZB) )
#define CB (BB * 12)     // compute blocks   (blocks [ZB, ZB+CB) ), 12 tiles/batch

// ---------------- Kernel A: fused zero-fill + IoU/argmax/deltas/packed -------
// Block roles: [0,ZB) stream zeros over ALL of d_out (grid-stride, many
// stores/thread); [ZB, ZB+CB) compute per-roi packed masks + deltas.
// packed[n] = posmult(11b) | negmult(11b)<<11 | gtlabel(5b)<<22
__global__ __launch_bounds__(256) void kA(
    const float4* __restrict__ roi, const float4* __restrict__ gt,
    const int* __restrict__ gtl, const int* __restrict__ rpos,
    const int* __restrict__ rneg, int* __restrict__ packed,
    float4* __restrict__ deltas, float4* __restrict__ outz)
{
  #pragma clang fp contract(off)
  const int tid = threadIdx.x;

  if (blockIdx.x < ZB) {
    // ---- zero role: 5,040,000 float4 over 262,144 threads = ~19 stores each
    const float4 z = make_float4(0.f, 0.f, 0.f, 0.f);
    const int total4 = BB * NN * 21 * 5 / 4;     // 5,040,000
    for (int i = blockIdx.x * 256 + tid; i < total4; i += ZB * 256)
      outz[i] = z;
    return;
  }

  // ---- compute role
  const int cb = blockIdx.x - ZB;
  const int b = cb / 12;
  const int n = (cb % 12) * 256 + tid;
  const bool valid = (n < NN);
  __shared__ float4 g[MM];
  __shared__ float  ga[MM];
  __shared__ int    gl[MM];

  float4 r = roi[b * NN + (valid ? n : 0)];
  if (tid < MM) {
    float4 v = gt[b * MM + tid];
    g[tid]  = v;
    ga[tid] = (v.z - v.x) * (v.w - v.y);
    gl[tid] = gtl[b * MM + tid];
  }
  __syncthreads();
  if (!valid) return;

  float ar = (r.z - r.x) * (r.w - r.y);
  float best = -1.0f; int bi = 0;
  #pragma unroll 4
  for (int m = 0; m < MM; ++m) {
    float4 gm = g[m];
    float iy1 = fmaxf(r.x, gm.x);
    float ix1 = fmaxf(r.y, gm.y);
    float iy2 = fminf(r.z, gm.z);
    float ix2 = fminf(r.w, gm.w);
    float inter = fmaxf(iy2 - iy1, 0.0f) * fmaxf(ix2 - ix1, 0.0f);
    float iou = inter / (ar + ga[m] - inter + 1e-7f);  // IEEE div = np bitwise
    if (iou > best) { best = iou; bi = m; }            // strict > = first argmax
  }
  int pm = (best > 0.5f) ? rpos[b * NN + n] : 0;
  int nm = (best < 0.5f && best > 0.1f) ? rneg[b * NN + n] : 0;
  packed[b * NN + n] = pm | (nm << 11) | (gl[bi] << 22);

  float4 gg = g[bi];
  float bw = r.w - r.y, bh = r.z - r.x;
  float bcx = r.y + 0.5f * bw, bcy = r.x + 0.5f * bh;
  float gw = gg.w - gg.y, gh = gg.z - gg.x;
  float gcx = gg.y + 0.5f * gw, gcy = gg.x + 0.5f * gh;
  bw = (bw == 0.0f) ? 0.001f : bw;
  bh = (bh == 0.0f) ? 0.001f : bh;
  float dx = (gw == 0.0f) ? 0.0f : (gcx - bcx) / bw;
  float dy = (gh == 0.0f) ? 0.0f : (gcy - bcy) / bh;
  float dw = (gw == 0.0f) ? 0.0f : logf(gw / bw);
  float dh = (gh == 0.0f) ? 0.0f : logf(gh / bh);
  deltas[b * NN + n] = make_float4(dy / 0.1f, dx / 0.1f, dh / 0.2f, dw / 0.2f);
}

// ---------------- Kernel B: top-128 selection + SPARSE scatter ---------------
// rank = position in stable descending sort of mask*rand; selected iff
// masked && rank < 128 (ties by lowest index). Scatters <=256 nonzeros
// per batch into the pre-zeroed outputs.
__global__ __launch_bounds__(1024) void kB(
    const int* __restrict__ packed, const float4* __restrict__ deltas,
    float4* __restrict__ out1, float* __restrict__ out2)
{
  const int b = blockIdx.x;
  const int tid = threadIdx.x;
  const int lane = tid & 63;
  const int wave = tid >> 6;
  __shared__ int sp[NN];
  __shared__ unsigned hist[NBINS + 1];  // pos count low16 | neg count high16
  __shared__ unsigned wsum[16];
  __shared__ int sT[4];                 // Tp, Qp, Tn, Qn

  for (int i = tid; i < NBINS + 1; i += 1024) hist[i] = 0;
  if (tid == 0) { sT[0] = 0; sT[1] = 0; sT[2] = 0; sT[3] = 0; }
  __syncthreads();

  for (int i = tid; i < NN; i += 1024) {
    int p = packed[b * NN + i];
    sp[i] = p;
    int pm = p & 0x7FF, nm = (p >> 11) & 0x7FF;
    if (pm) atomicAdd(&hist[pm], 1u);
    if (nm) atomicAdd(&hist[nm], 0x10000u);
  }
  __syncthreads();

  // single-wave register suffix scan over 1280 bins (20 bins/lane, packed)
  if (wave == 0) {
    unsigned cs[21];
    const int base = 1 + lane * 20;
    cs[20] = 0;
    #pragma unroll
    for (int j = 19; j >= 0; --j) cs[j] = cs[j + 1] + hist[base + j];
    unsigned tot = cs[0];
    unsigned run = tot;
    #pragma unroll
    for (int off = 1; off < 64; off <<= 1) {
      unsigned u = __shfl_down(run, off);
      if (lane + off < 64) run += u;
    }
    unsigned above = run - tot;  // suffix over lanes > lane
    #pragma unroll
    for (int j = 0; j < 20; ++j) {
      int bin = base + j;
      unsigned s  = cs[j] + above;
      unsigned sn = cs[j + 1] + above;
      unsigned ps = s & 0xFFFFu, psn = sn & 0xFFFFu;
      if (ps >= NSEL && psn < NSEL) { sT[0] = bin; sT[1] = NSEL - (int)psn; }
      unsigned ns = s >> 16, nsn = sn >> 16;
      if (ns >= NSEL && nsn < NSEL) { sT[2] = bin; sT[3] = NSEL - (int)nsn; }
    }
  }
  __syncthreads();
  const int Tp = sT[0], Qp = sT[1], Tn = sT[2], Qn = sT[3];

  // tie-rank: thread t owns contiguous chunk [3t, 3t+3)
  const int n0 = tid * 3;
  int q[3] = {0, 0, 0};
  if (n0     < NN) q[0] = sp[n0];
  if (n0 + 1 < NN) q[1] = sp[n0 + 1];
  if (n0 + 2 < NN) q[2] = sp[n0 + 2];
  unsigned cc = 0;
  #pragma unroll
  for (int j = 0; j < 3; ++j) {
    int pm = q[j] & 0x7FF, nm = (q[j] >> 11) & 0x7FF;
    if (Tp && pm == Tp) cc += 1u;
    if (Tn && nm == Tn) cc += 0x10000u;
  }
  unsigned inc = cc;
  #pragma unroll
  for (int off = 1; off < 64; off <<= 1) {
    unsigned u = __shfl_up(inc, off);
    if (lane >= off) inc += u;
  }
  if (lane == 63) wsum[wave] = inc;
  __syncthreads();
  unsigned woff = 0;
  for (int w = 0; w < wave; ++w) woff += wsum[w];
  unsigned excl = woff + (inc - cc);
  int ep = (int)(excl & 0xFFFFu), en = (int)(excl >> 16);

  // selection + sparse scatter into pre-zeroed outputs
  #pragma unroll
  for (int j = 0; j < 3; ++j) {
    int n = n0 + j;
    if (n >= NN) break;
    int p = q[j];
    int pm = p & 0x7FF, nm = (p >> 11) & 0x7FF;
    bool selp;
    if (pm > Tp) selp = true;
    else if (pm && pm == Tp) { selp = (ep < Qp); ep++; }
    else selp = false;
    bool seln;
    if (nm > Tn) seln = true;
    else if (nm && nm == Tn) { seln = (en < Qn); en++; }
    else seln = false;
    if (selp | seln) {
      size_t nl = (size_t)b * NN + n;
      int lab = selp ? ((p >> 22) & 0x1F) : 0;
      out2[nl * 21 + lab] = 1.0f;
      if (lab > 0) out1[nl * 21 + lab] = deltas[nl];
    }
  }
}

extern "C" void kernel_launch(void* const* d_in, const int* in_sizes, int n_in,
                              void* d_out, int out_size, void* d_ws, size_t ws_size,
                              hipStream_t stream) {
  const float4* roi = (const float4*)d_in[0];
  const float4* gt  = (const float4*)d_in[1];
  const int* gtl  = (const int*)d_in[2];
  const int* rpos = (const int*)d_in[3];
  const int* rneg = (const int*)d_in[4];

  char* ws = (char*)d_ws;
  int*    packed = (int*)ws;                    // B*N ints (768 KB)
  float4* deltas = (float4*)(ws + (1 << 20));   // B*N float4 (3 MB)

  float4* out1 = (float4*)d_out;                            // B*N*21 float4
  float*  out2 = (float*)d_out + (size_t)BB * NN * 21 * 4;  // B*N*21 floats

  kA<<<ZB + CB, 256, 0, stream>>>(roi, gt, gtl, rpos, rneg, packed, deltas,
                                  (float4*)d_out);
  kB<<<BB, 1024, 0, stream>>>(packed, deltas, out1, out2);
}